// Round 17
// baseline (106.249 us; speedup 1.0000x reference)
//
#include <hip/hip_runtime.h>
#include <hip/hip_bf16.h>

#define B_  1024
#define LA  529   // token positions -> conv channels
#define EE  100   // embedding dim -> conv steps
#define NF  16    // conv filters
#define NT  50    // conv output steps
#define NS  25    // pooled steps
#define NU  100   // LSTM units
#define NJ  400   // 4*NU

typedef float    f32x4v __attribute__((ext_vector_type(4)));
typedef short    s16x8  __attribute__((ext_vector_type(8)));
typedef _Float16 h2v    __attribute__((ext_vector_type(2)));
typedef _Float16 h16x8  __attribute__((ext_vector_type(8)));

__device__ __forceinline__ float leaky(float v) { return v >= 0.f ? v : 0.2f * v; }

__device__ __forceinline__ unsigned int pkh2(float x, float y) {
    auto p = __builtin_amdgcn_cvt_pkrtz(x, y);
    return __builtin_bit_cast(unsigned int, p);
}
__device__ __forceinline__ unsigned short f2h(float x) {
    return __builtin_bit_cast(unsigned short, (_Float16)x);
}
__device__ __forceinline__ float fdot2h(unsigned int e, unsigned int w, float acc) {
#if __has_builtin(__builtin_amdgcn_fdot2)
    return __builtin_amdgcn_fdot2(__builtin_bit_cast(h2v, e),
                                  __builtin_bit_cast(h2v, w), acc, false);
#else
    h2v ev = __builtin_bit_cast(h2v, e), wv = __builtin_bit_cast(h2v, w);
    return acc + (float)ev.x * (float)wv.x + (float)ev.y * (float)wv.y;
#endif
}

// ---------------- Kernel P: fp32 -> fp16 conversion ----------------
__global__ __launch_bounds__(256) void prep_kernel(
    const float* __restrict__ emb,      // [V*E]
    const float* __restrict__ conv_w,   // [2][529][16]
    unsigned int* __restrict__ emb_h,   // [V*E/2] packed half2
    unsigned int* __restrict__ convw_h) // [529*16] packed (w0,w1)
{
    const int gid = blockIdx.x * 256 + threadIdx.x;
    const int stride = gridDim.x * 256;
    for (int i = gid; i < (15245 * 100) / 2; i += stride) {
        const float2 v = ((const float2*)emb)[i];
        emb_h[i] = pkh2(v.x, v.y);
    }
    for (int i = gid; i < LA * NF; i += stride)
        convw_h[i] = pkh2(conv_w[i], conv_w[LA * NF + i]);
}

// ---------------- Kernel A: gather + conv + relu + maxpool ----------------
// 256 blocks x 512 threads, block = 4 batches. Wave w owns cols
// [67w, 67w+NC) and processes ALL 4 batches per weight read: one 4xb128
// LDS broadcast feeds 64 fdot2 (4x fewer LDS reads per batch than r16 —
// the measured 40us was exactly the LDS weight-broadcast pipe).
// Cross-wave reduction via conflict-free ds_add_f32 into f-major y.
__global__ __launch_bounds__(512, 2) void conv_embed_kernel(
    const int*          __restrict__ tokens,
    const unsigned int* __restrict__ emb_h,   // [V][50] half2 rows
    const unsigned int* __restrict__ convw_h, // [529][16] (w0,w1) half2
    const float*        __restrict__ conv_b,
    float*              __restrict__ p_out)   // [B][25][16]
{
    __shared__ __align__(16) unsigned int wlds[LA * NF];  // 33.9 KB
    __shared__ float y[4][NF][52];                        // 13.3 KB, f-major

    const int tid  = threadIdx.x;
    const int lane = tid & 63;
    const int w    = __builtin_amdgcn_readfirstlane(tid >> 6);  // 0..7
    const int b0   = blockIdx.x * 4;
    const int t    = lane < NT ? lane : (NT - 1);

    for (int i = tid; i < (LA * NF) / 4; i += 512)
        ((uint4*)wlds)[i] = ((const uint4*)convw_h)[i];
    for (int i = tid; i < 4 * NF * 52; i += 512) ((float*)y)[i] = 0.f;
    __syncthreads();

    const int cbase = w * 67;
    const int NC    = (LA - cbase) < 67 ? (LA - cbase) : 67;   // 67 or 60
    const int* __restrict__ tokb = tokens + (size_t)b0 * LA;

    float acc[4][NF];   // 64 VGPR
#pragma unroll
    for (int bb = 0; bb < 4; ++bb)
#pragma unroll
        for (int f = 0; f < NF; ++f) acc[bb][f] = 0.f;

#define LOADE(dst, i_) do { \
    const int ii = (i_); \
    const int cc = cbase + (ii < NC ? ii : 0); \
    _Pragma("unroll") \
    for (int bb = 0; bb < 4; ++bb) { \
        unsigned int v = emb_h[(size_t)tokb[bb * LA + cc] * 50 + t]; \
        if (ii >= NC) v = 0u; \
        (dst)[bb] = v; \
    } } while (0)

    unsigned int ebuf[4][4];   // [pf][bb]
#pragma unroll
    for (int j = 0; j < 4; ++j) LOADE(ebuf[j], j);

    for (int ig = 0; ig < 68; ig += 4) {   // 17 groups cover i = 0..67 >= NC
        unsigned int enxt[4][4];
#pragma unroll
        for (int j = 0; j < 4; ++j) LOADE(enxt[j], ig + 4 + j);
#pragma unroll
        for (int j = 0; j < 4; ++j) {
            const int i  = ig + j;
            const int cc = cbase + ((i < NC) ? i : 0);   // padded cols: e=0
            const unsigned int* wp = wlds + cc * NF;
            unsigned int wv[NF];
#pragma unroll
            for (int q = 0; q < 4; ++q) ((uint4*)wv)[q] = ((const uint4*)wp)[q];
#pragma unroll
            for (int bb = 0; bb < 4; ++bb)
#pragma unroll
                for (int f = 0; f < NF; ++f)
                    acc[bb][f] = fdot2h(ebuf[j][bb], wv[f], acc[bb][f]);
        }
#pragma unroll
        for (int j = 0; j < 4; ++j)
#pragma unroll
            for (int bb = 0; bb < 4; ++bb) ebuf[j][bb] = enxt[j][bb];
    }
#undef LOADE

    if (lane < NT) {
#pragma unroll
        for (int bb = 0; bb < 4; ++bb)
#pragma unroll
            for (int f = 0; f < NF; ++f)
                atomicAdd(&y[bb][f][t], acc[bb][f]);   // bank = t: conflict-free
    }
    __syncthreads();

    // bias + relu + maxpool (relu(max(y0,y1)+b) == max(relu(y0+b),relu(y1+b)))
    for (int idx = tid; idx < 4 * NS * NF; idx += 512) {
        const int bb = idx / 400, r = idx - bb * 400;
        const int s = r >> 4, f = r & 15;
        const float m = fmaxf(y[bb][f][2 * s], y[bb][f][2 * s + 1]);
        p_out[(size_t)(b0 + bb) * (NS * NF) + r] = fmaxf(m + conv_b[f], 0.f);
    }
}

// ---------------- Kernel B: fp16 MFMA LSTM, 2 tiles/wave ------------------
// (r15 proven, ~36us: 256 blocks x 896 threads, 4 batches/block, 32-VGPR
// stationary B per wave — the first set the allocator kept resident.)
__global__ __launch_bounds__(896) void lstm_mfma_kernel(
    const float* __restrict__ p_in,    // [B][25][16]
    const float* __restrict__ k_lstm,  // [16][400]
    const float* __restrict__ rk,      // [100][400]
    const float* __restrict__ b_lstm,  // [400]
    const float* __restrict__ w1,      // [100][64]
    const float* __restrict__ b1,      // [64]
    const float* __restrict__ w2,      // [64][3]
    const float* __restrict__ b2,      // [3]
    float*       __restrict__ out)     // [B][3]
{
    __shared__ __align__(16) unsigned short a_lds[2][4][64][8]; // dbuf, 8 KB
    __shared__ __align__(16) float z_lds[NJ][4];                // [j][b], 6.4 KB
    __shared__ float h_f32[4][NU];
    __shared__ float d_lds[4 * 64];

    const int tid  = threadIdx.x;
    const int lane = tid & 63;
    const int wid  = tid >> 6;
    const int b0   = blockIdx.x * 4;

    for (int i = tid; i < 2 * 4 * 64 * 8; i += 896) ((unsigned short*)a_lds)[i] = 0;

    // ---- stationary B-frags (fp16): wave w owns tiles {2w, 2w+1} ----
    h16x8 bfr[2][4];   // [tile][chunk] = 32 VGPR
#pragma unroll
    for (int i = 0; i < 2; ++i) {
        const int ntg = wid * 2 + i;
        if (ntg < 25) {
            const int jg = ntg * 16 + (lane & 15);
#pragma unroll
            for (int c = 0; c < 4; ++c) {
                h16x8 h8;
#pragma unroll
                for (int e = 0; e < 8; ++e) {
                    const int k = c * 32 + (lane >> 4) * 8 + e;
                    float x = 0.f;
                    if (k < NU)        x = rk[k * NJ + jg];
                    else if (k < 116)  x = k_lstm[(k - NU) * NJ + jg];
                    else if (k == 116) x = b_lstm[jg];
                    h8[e] = (_Float16)x;
                }
                bfr[i][c] = h8;
            }
        }
    }
    __syncthreads();   // a_lds zeroing complete

    // initial p (t=0): 64 slots (4 batches x 16); bias slot k=116 both buffers
    if (tid < 64) {
        const int pb = tid >> 4, pf = tid & 15;
        const float pv = p_in[(size_t)(b0 + pb) * (NS * NF) + pf];
        const int k = 100 + pf;
        a_lds[0][k >> 5][(((k >> 3) & 3) << 4) + pb][k & 7] = f2h(pv);
    }
    if (tid < 4) {
        a_lds[0][3][32 + tid][4] = 0x3C00;   // fp16 1.0
        a_lds[1][3][32 + tid][4] = 0x3C00;
    }
    float cst = 0.f;
    const int gb = tid & 3, gu = tid >> 2;   // gate thread (tid < 400)
    __syncthreads();

#pragma unroll 1
    for (int t = 0; t < NS; ++t) {
        const int cur = t & 1, nxt = cur ^ 1;
        // wave 13: prefetch p for t+1 (overlaps compute)
        float pv = 0.f;
        if (tid >= 832 && t + 1 < NS) {
            const int idx = tid - 832, pb = idx >> 4, pf = idx & 15;
            pv = p_in[(size_t)(b0 + pb) * (NS * NF) + (t + 1) * NF + pf];
        }
        if (wid < 13) {   // waves 0..12 compute
            h16x8 ah[4];
#pragma unroll
            for (int c = 0; c < 4; ++c)
                ah[c] = __builtin_bit_cast(h16x8, ((const s16x8*)a_lds[cur][c])[lane]);
#pragma unroll
            for (int i = 0; i < 2; ++i) {
                const int ntg = wid * 2 + i;
                if (ntg < 25) {
                    f32x4v z0 = {0.f, 0.f, 0.f, 0.f}, z1 = {0.f, 0.f, 0.f, 0.f};
                    z0 = __builtin_amdgcn_mfma_f32_16x16x32_f16(ah[0], bfr[i][0], z0, 0, 0, 0);
                    z1 = __builtin_amdgcn_mfma_f32_16x16x32_f16(ah[1], bfr[i][1], z1, 0, 0, 0);
                    z0 = __builtin_amdgcn_mfma_f32_16x16x32_f16(ah[2], bfr[i][2], z0, 0, 0, 0);
                    z1 = __builtin_amdgcn_mfma_f32_16x16x32_f16(ah[3], bfr[i][3], z1, 0, 0, 0);
                    const f32x4v acc = z0 + z1;
                    if (lane < 16) {   // rows 0..3 = real batches
                        *((f32x4v*)z_lds[ntg * 16 + lane]) = acc;
                    }
                }
            }
        }
        __syncthreads();
        // gates: thread -> (b = tid&3, u = tid>>2)
        if (tid < 4 * NU) {
            const float zi = z_lds[gu][gb];
            const float zf = z_lds[gu + 100][gb];
            const float zg = z_lds[gu + 200][gb];
            const float zo = z_lds[gu + 300][gb];
            const float ig  = 1.f / (1.f + __expf(-zi));
            const float fg_ = 1.f / (1.f + __expf(-zf));
            const float og  = 1.f / (1.f + __expf(-zo));
            cst = fg_ * cst + ig * leaky(zg);
            const float h = og * leaky(cst);
            h_f32[gb][gu] = h;
            const int c = gu >> 5, ls = (((gu >> 3) & 3) << 4) + gb, e = gu & 7;
            a_lds[nxt][c][ls][e] = f2h(h);
        }
        if (tid >= 832 && t + 1 < NS) {   // write p slots for t+1
            const int idx = tid - 832, pb = idx >> 4, pf = idx & 15;
            const int k = 100 + pf;
            a_lds[nxt][k >> 5][(((k >> 3) & 3) << 4) + pb][k & 7] = f2h(pv);
        }
        __syncthreads();
    }

    // dense head: d = tanh(h @ w1 + b1)
    if (tid < 256) {
        const int hb = tid >> 6, m = tid & 63;
        float a = b1[m];
#pragma unroll 4
        for (int u = 0; u < NU; ++u) a += h_f32[hb][u] * w1[u * 64 + m];
        d_lds[hb * 64 + m] = tanhf(a);
    }
    __syncthreads();

    // logits + softmax (3 classes)
    if (tid < 4) {
        float l0 = b2[0], l1 = b2[1], l2 = b2[2];
        for (int m = 0; m < 64; ++m) {
            const float d = d_lds[tid * 64 + m];
            l0 += d * w2[m * 3 + 0];
            l1 += d * w2[m * 3 + 1];
            l2 += d * w2[m * 3 + 2];
        }
        const float mx = fmaxf(l0, fmaxf(l1, l2));
        const float e0 = __expf(l0 - mx), e1 = __expf(l1 - mx), e2 = __expf(l2 - mx);
        const float inv = 1.f / (e0 + e1 + e2);
        out[(b0 + tid) * 3 + 0] = e0 * inv;
        out[(b0 + tid) * 3 + 1] = e1 * inv;
        out[(b0 + tid) * 3 + 2] = e2 * inv;
    }
}

extern "C" void kernel_launch(void* const* d_in, const int* in_sizes, int n_in,
                              void* d_out, int out_size, void* d_ws, size_t ws_size,
                              hipStream_t stream) {
    const int*   tokens = (const int*)  d_in[0];
    const float* emb    = (const float*)d_in[1];
    const float* conv_w = (const float*)d_in[2];
    const float* conv_b = (const float*)d_in[3];
    const float* k_lstm = (const float*)d_in[4];
    const float* rk     = (const float*)d_in[5];
    const float* b_lstm = (const float*)d_in[6];
    const float* w1     = (const float*)d_in[7];
    const float* b1     = (const float*)d_in[8];
    const float* w2     = (const float*)d_in[9];
    const float* b2     = (const float*)d_in[10];
    float* out = (float*)d_out;

    // ws layout (bytes): p[1024][25][16] f32 : [0, 1638400)
    //                    emb_h (half2)       : [1638400, 4687400) -> align 4687408
    //                    convw_h (half2)     : [4687408, 4721264)
    char* ws = (char*)d_ws;
    float*        p_ws    = (float*)ws;
    unsigned int* emb_h   = (unsigned int*)(ws + 1638400);
    unsigned int* convw_h = (unsigned int*)(ws + 4687408);

    prep_kernel<<<1024, 256, 0, stream>>>(emb, conv_w, emb_h, convw_h);
    conv_embed_kernel<<<B_ / 4, 512, 0, stream>>>(tokens, emb_h, convw_h, conv_b, p_ws);
    lstm_mfma_kernel<<<B_ / 4, 896, 0, stream>>>(p_ws, k_lstm, rk, b_lstm,
                                                 w1, b1, w2, b2, out);
}

// Round 18
// 76.903 us; speedup vs baseline: 1.3816x; 1.3816x over previous
//
#include <hip/hip_runtime.h>
#include <hip/hip_bf16.h>

#define B_  1024
#define LA  529   // token positions -> conv channels
#define EE  100   // embedding dim -> conv steps
#define NF  16    // conv filters
#define NT  50    // conv output steps
#define NS  25    // pooled steps
#define NU  100   // LSTM units
#define NJ  400   // 4*NU
#define PF  8     // e-prefetch depth

typedef float    f32x4v __attribute__((ext_vector_type(4)));
typedef short    s16x8  __attribute__((ext_vector_type(8)));
typedef _Float16 h2v    __attribute__((ext_vector_type(2)));
typedef _Float16 h16x8  __attribute__((ext_vector_type(8)));

__device__ __forceinline__ float leaky(float v) { return v >= 0.f ? v : 0.2f * v; }

__device__ __forceinline__ unsigned int pkh2(float x, float y) {
    auto p = __builtin_amdgcn_cvt_pkrtz(x, y);
    return __builtin_bit_cast(unsigned int, p);
}
__device__ __forceinline__ unsigned short f2h(float x) {
    return __builtin_bit_cast(unsigned short, (_Float16)x);
}
__device__ __forceinline__ float fdot2h(unsigned int e, unsigned int w, float acc) {
#if __has_builtin(__builtin_amdgcn_fdot2)
    return __builtin_amdgcn_fdot2(__builtin_bit_cast(h2v, e),
                                  __builtin_bit_cast(h2v, w), acc, false);
#else
    h2v ev = __builtin_bit_cast(h2v, e), wv = __builtin_bit_cast(h2v, w);
    return acc + (float)ev.x * (float)wv.x + (float)ev.y * (float)wv.y;
#endif
}

// ---------------- Kernel P: fp32 -> fp16 conversion ----------------
__global__ __launch_bounds__(256) void prep_kernel(
    const float* __restrict__ emb,      // [V*E]
    const float* __restrict__ conv_w,   // [2][529][16]
    unsigned int* __restrict__ emb_h,   // [V*E/2] packed half2
    unsigned int* __restrict__ convw_h) // [529*16] packed (w0,w1)
{
    const int gid = blockIdx.x * 256 + threadIdx.x;
    const int stride = gridDim.x * 256;
    for (int i = gid; i < (15245 * 100) / 2; i += stride) {
        const float2 v = ((const float2*)emb)[i];
        emb_h[i] = pkh2(v.x, v.y);
    }
    for (int i = gid; i < LA * NF; i += stride)
        convw_h[i] = pkh2(conv_w[i], conv_w[LA * NF + i]);
}

// ---------------- Kernel A: gather + conv + relu + maxpool ----------------
// r16 structure (best measured, 40.7us) + LDS token staging: 512 blocks x
// 512 threads, 2 batches/block; waves 0..3 -> batch b0, waves 4..7 ->
// batch b0+1; wave w owns contiguous cols [133w, 133w+NC).
// NEW: both batches' tokens staged into LDS once (1 coalesced read) —
// breaks the global-token -> global-e dependent chain that left VALUBusy
// at 40% (token access is now an lgkm-counter LDS broadcast, decoupled
// from the vm-counter e-load pipeline).
__global__ __launch_bounds__(512) void conv_embed_kernel(
    const int*          __restrict__ tokens,
    const unsigned int* __restrict__ emb_h,   // [V][50] half2 rows
    const unsigned int* __restrict__ convw_h, // [529][16] (w0,w1) half2
    const float*        __restrict__ conv_b,
    float*              __restrict__ p_out)   // [B][25][16]
{
    __shared__ __align__(16) unsigned int smem[LA * NF];  // 33.9 KB arena
    __shared__ int tok2[2 * LA];                          // 4.2 KB
    unsigned int* wlds = smem;
    float* part = (float*)smem;            // [2][4][50][16] = 25.6 KB (overlay)
    float* ylds = (float*)smem + 6400;     // [2][50][16] = 6.4 KB (overlay)

    const int tid  = threadIdx.x;
    const int lane = tid & 63;
    const int wv8  = __builtin_amdgcn_readfirstlane(tid >> 6);  // 0..7
    const int wb   = wv8 >> 2;             // batch half 0/1
    const int w    = wv8 & 3;              // column-range id 0..3
    const int t    = lane < NT ? lane : (NT - 1);

    for (int i = tid; i < (LA * NF) / 4; i += 512)
        ((uint4*)smem)[i] = ((const uint4*)convw_h)[i];
    for (int i = tid; i < 2 * LA; i += 512)
        tok2[i] = tokens[(size_t)blockIdx.x * 2 * LA + i];
    __syncthreads();

    const int cbase = w * 133;
    const int NC    = (w < 3) ? 133 : 130;
    const int* __restrict__ tokb = tok2 + wb * LA + cbase;

    float acc[NF];
#pragma unroll
    for (int f = 0; f < NF; ++f) acc[f] = 0.f;

#define LOAD_E(dst, i_) do { \
    const int i2 = (i_); \
    const int ic = (i2 < NC) ? i2 : 0; \
    unsigned int v = emb_h[(size_t)tokb[ic] * 50 + t]; \
    if (i2 >= NC) v = 0u; \
    (dst) = v; } while (0)

    unsigned int ebuf[PF];
#pragma unroll
    for (int j = 0; j < PF; ++j) LOAD_E(ebuf[j], j);

    for (int ig = 0; ig < 136; ig += PF) {
        unsigned int enxt[PF];
#pragma unroll
        for (int j = 0; j < PF; ++j) LOAD_E(enxt[j], ig + PF + j);
#pragma unroll
        for (int j = 0; j < PF; ++j) {
            const int i  = ig + j;
            const int cc = cbase + ((i < NC) ? i : 0);
            const unsigned int* wp = wlds + cc * NF;
            unsigned int wvv[NF];
#pragma unroll
            for (int q = 0; q < 4; ++q) ((uint4*)wvv)[q] = ((const uint4*)wp)[q];
#pragma unroll
            for (int f = 0; f < NF; ++f) acc[f] = fdot2h(ebuf[j], wvv[f], acc[f]);
        }
#pragma unroll
        for (int j = 0; j < PF; ++j) ebuf[j] = enxt[j];
    }
#undef LOAD_E

    __syncthreads();   // all waves done reading wlds; arena becomes part/y
    if (lane < NT) {
        float4* dst = (float4*)(part + (size_t)((wb * 4 + w) * NT + lane) * NF);
#pragma unroll
        for (int q = 0; q < 4; ++q) dst[q] = ((float4*)acc)[q];
    }
    __syncthreads();

    // reduce 4 wave-partials + bias + relu -> y[2][50][16]
    if (tid < 400) {
        const int bb = tid / 200, r = tid - bb * 200;
        const int tr = r >> 2, fq = r & 3;
        const float* pb_ = part + (size_t)(bb * 4) * NT * NF;
        float4 s0 = ((float4*)(pb_ + (0 * NT + tr) * NF))[fq];
        float4 s1 = ((float4*)(pb_ + (1 * NT + tr) * NF))[fq];
        float4 s2 = ((float4*)(pb_ + (2 * NT + tr) * NF))[fq];
        float4 s3 = ((float4*)(pb_ + (3 * NT + tr) * NF))[fq];
        float4 cb = ((const float4*)conv_b)[fq];
        float4 y;
        y.x = fmaxf(s0.x + s1.x + s2.x + s3.x + cb.x, 0.f);
        y.y = fmaxf(s0.y + s1.y + s2.y + s3.y + cb.y, 0.f);
        y.z = fmaxf(s0.z + s1.z + s2.z + s3.z + cb.z, 0.f);
        y.w = fmaxf(s0.w + s1.w + s2.w + s3.w + cb.w, 0.f);
        ((float4*)(ylds + (bb * NT + tr) * NF))[fq] = y;
    }
    __syncthreads();

    // maxpool k=2 s=2 -> p[2][25][16]
    for (int idx = tid; idx < 2 * NS * NF; idx += 512) {
        const int bb = idx / 400, r = idx - bb * 400;
        const int s = r >> 4, f = r & 15;
        p_out[(size_t)(blockIdx.x * 2 + bb) * (NS * NF) + r] =
            fmaxf(ylds[(bb * NT + 2 * s) * NF + f],
                  ylds[(bb * NT + 2 * s + 1) * NF + f]);
    }
}

// ---------------- Kernel B: fp16 MFMA LSTM, 2 tiles/wave ------------------
// (r15 proven: 256 blocks x 896 threads, 4 batches/block, 32-VGPR
// stationary B per wave — the first set the allocator kept resident.)
__global__ __launch_bounds__(896) void lstm_mfma_kernel(
    const float* __restrict__ p_in,    // [B][25][16]
    const float* __restrict__ k_lstm,  // [16][400]
    const float* __restrict__ rk,      // [100][400]
    const float* __restrict__ b_lstm,  // [400]
    const float* __restrict__ w1,      // [100][64]
    const float* __restrict__ b1,      // [64]
    const float* __restrict__ w2,      // [64][3]
    const float* __restrict__ b2,      // [3]
    float*       __restrict__ out)     // [B][3]
{
    __shared__ __align__(16) unsigned short a_lds[2][4][64][8]; // dbuf, 8 KB
    __shared__ __align__(16) float z_lds[NJ][4];                // [j][b], 6.4 KB
    __shared__ float h_f32[4][NU];
    __shared__ float d_lds[4 * 64];

    const int tid  = threadIdx.x;
    const int lane = tid & 63;
    const int wid  = tid >> 6;
    const int b0   = blockIdx.x * 4;

    for (int i = tid; i < 2 * 4 * 64 * 8; i += 896) ((unsigned short*)a_lds)[i] = 0;

    // ---- stationary B-frags (fp16): wave w owns tiles {2w, 2w+1} ----
    h16x8 bfr[2][4];   // [tile][chunk] = 32 VGPR
#pragma unroll
    for (int i = 0; i < 2; ++i) {
        const int ntg = wid * 2 + i;
        if (ntg < 25) {
            const int jg = ntg * 16 + (lane & 15);
#pragma unroll
            for (int c = 0; c < 4; ++c) {
                h16x8 h8;
#pragma unroll
                for (int e = 0; e < 8; ++e) {
                    const int k = c * 32 + (lane >> 4) * 8 + e;
                    float x = 0.f;
                    if (k < NU)        x = rk[k * NJ + jg];
                    else if (k < 116)  x = k_lstm[(k - NU) * NJ + jg];
                    else if (k == 116) x = b_lstm[jg];
                    h8[e] = (_Float16)x;
                }
                bfr[i][c] = h8;
            }
        }
    }
    __syncthreads();   // a_lds zeroing complete

    // initial p (t=0): 64 slots (4 batches x 16); bias slot k=116 both buffers
    if (tid < 64) {
        const int pb = tid >> 4, pf = tid & 15;
        const float pv = p_in[(size_t)(b0 + pb) * (NS * NF) + pf];
        const int k = 100 + pf;
        a_lds[0][k >> 5][(((k >> 3) & 3) << 4) + pb][k & 7] = f2h(pv);
    }
    if (tid < 4) {
        a_lds[0][3][32 + tid][4] = 0x3C00;   // fp16 1.0
        a_lds[1][3][32 + tid][4] = 0x3C00;
    }
    float cst = 0.f;
    const int gb = tid & 3, gu = tid >> 2;   // gate thread (tid < 400)
    __syncthreads();

#pragma unroll 1
    for (int t = 0; t < NS; ++t) {
        const int cur = t & 1, nxt = cur ^ 1;
        // wave 13: prefetch p for t+1 (overlaps compute)
        float pv = 0.f;
        if (tid >= 832 && t + 1 < NS) {
            const int idx = tid - 832, pb = idx >> 4, pf = idx & 15;
            pv = p_in[(size_t)(b0 + pb) * (NS * NF) + (t + 1) * NF + pf];
        }
        if (wid < 13) {   // waves 0..12 compute
            h16x8 ah[4];
#pragma unroll
            for (int c = 0; c < 4; ++c)
                ah[c] = __builtin_bit_cast(h16x8, ((const s16x8*)a_lds[cur][c])[lane]);
#pragma unroll
            for (int i = 0; i < 2; ++i) {
                const int ntg = wid * 2 + i;
                if (ntg < 25) {
                    f32x4v z0 = {0.f, 0.f, 0.f, 0.f}, z1 = {0.f, 0.f, 0.f, 0.f};
                    z0 = __builtin_amdgcn_mfma_f32_16x16x32_f16(ah[0], bfr[i][0], z0, 0, 0, 0);
                    z1 = __builtin_amdgcn_mfma_f32_16x16x32_f16(ah[1], bfr[i][1], z1, 0, 0, 0);
                    z0 = __builtin_amdgcn_mfma_f32_16x16x32_f16(ah[2], bfr[i][2], z0, 0, 0, 0);
                    z1 = __builtin_amdgcn_mfma_f32_16x16x32_f16(ah[3], bfr[i][3], z1, 0, 0, 0);
                    const f32x4v acc = z0 + z1;
                    if (lane < 16) {   // rows 0..3 = real batches
                        *((f32x4v*)z_lds[ntg * 16 + lane]) = acc;
                    }
                }
            }
        }
        __syncthreads();
        // gates: thread -> (b = tid&3, u = tid>>2)
        if (tid < 4 * NU) {
            const float zi = z_lds[gu][gb];
            const float zf = z_lds[gu + 100][gb];
            const float zg = z_lds[gu + 200][gb];
            const float zo = z_lds[gu + 300][gb];
            const float ig  = 1.f / (1.f + __expf(-zi));
            const float fg_ = 1.f / (1.f + __expf(-zf));
            const float og  = 1.f / (1.f + __expf(-zo));
            cst = fg_ * cst + ig * leaky(zg);
            const float h = og * leaky(cst);
            h_f32[gb][gu] = h;
            const int c = gu >> 5, ls = (((gu >> 3) & 3) << 4) + gb, e = gu & 7;
            a_lds[nxt][c][ls][e] = f2h(h);
        }
        if (tid >= 832 && t + 1 < NS) {   // write p slots for t+1
            const int idx = tid - 832, pb = idx >> 4, pf = idx & 15;
            const int k = 100 + pf;
            a_lds[nxt][k >> 5][(((k >> 3) & 3) << 4) + pb][k & 7] = f2h(pv);
        }
        __syncthreads();
    }

    // dense head: d = tanh(h @ w1 + b1)
    if (tid < 256) {
        const int hb = tid >> 6, m = tid & 63;
        float a = b1[m];
#pragma unroll 4
        for (int u = 0; u < NU; ++u) a += h_f32[hb][u] * w1[u * 64 + m];
        d_lds[hb * 64 + m] = tanhf(a);
    }
    __syncthreads();

    // logits + softmax (3 classes)
    if (tid < 4) {
        float l0 = b2[0], l1 = b2[1], l2 = b2[2];
        for (int m = 0; m < 64; ++m) {
            const float d = d_lds[tid * 64 + m];
            l0 += d * w2[m * 3 + 0];
            l1 += d * w2[m * 3 + 1];
            l2 += d * w2[m * 3 + 2];
        }
        const float mx = fmaxf(l0, fmaxf(l1, l2));
        const float e0 = __expf(l0 - mx), e1 = __expf(l1 - mx), e2 = __expf(l2 - mx);
        const float inv = 1.f / (e0 + e1 + e2);
        out[(b0 + tid) * 3 + 0] = e0 * inv;
        out[(b0 + tid) * 3 + 1] = e1 * inv;
        out[(b0 + tid) * 3 + 2] = e2 * inv;
    }
}

extern "C" void kernel_launch(void* const* d_in, const int* in_sizes, int n_in,
                              void* d_out, int out_size, void* d_ws, size_t ws_size,
                              hipStream_t stream) {
    const int*   tokens = (const int*)  d_in[0];
    const float* emb    = (const float*)d_in[1];
    const float* conv_w = (const float*)d_in[2];
    const float* conv_b = (const float*)d_in[3];
    const float* k_lstm = (const float*)d_in[4];
    const float* rk     = (const float*)d_in[5];
    const float* b_lstm = (const float*)d_in[6];
    const float* w1     = (const float*)d_in[7];
    const float* b1     = (const float*)d_in[8];
    const float* w2     = (const float*)d_in[9];
    const float* b2     = (const float*)d_in[10];
    float* out = (float*)d_out;

    // ws layout (bytes): p[1024][25][16] f32 : [0, 1638400)
    //                    emb_h (half2)       : [1638400, 4687400) -> align 4687408
    //                    convw_h (half2)     : [4687408, 4721264)
    char* ws = (char*)d_ws;
    float*        p_ws    = (float*)ws;
    unsigned int* emb_h   = (unsigned int*)(ws + 1638400);
    unsigned int* convw_h = (unsigned int*)(ws + 4687408);

    prep_kernel<<<1024, 256, 0, stream>>>(emb, conv_w, emb_h, convw_h);
    conv_embed_kernel<<<B_ / 2, 512, 0, stream>>>(tokens, emb_h, convw_h, conv_b, p_ws);
    lstm_mfma_kernel<<<B_ / 4, 896, 0, stream>>>(p_ws, k_lstm, rk, b_lstm,
                                                 w1, b1, w2, b2, out);
}

// Round 19
// 57.886 us; speedup vs baseline: 1.8355x; 1.3285x over previous
//
#include <hip/hip_runtime.h>
#include <hip/hip_bf16.h>

#define B_  1024
#define LA  529   // token positions -> conv channels
#define EE  100   // embedding dim -> conv steps
#define NF  16    // conv filters
#define NT  50    // conv output steps
#define NS  25    // pooled steps
#define NU  100   // LSTM units
#define NJ  400   // 4*NU
#define NKC 34    // K-chunks of 32 (K = 2*529 = 1058, padded 1088)

typedef float        f32x4v __attribute__((ext_vector_type(4)));
typedef short        s16x8  __attribute__((ext_vector_type(8)));
typedef unsigned int u32x4  __attribute__((ext_vector_type(4)));
typedef _Float16     h2v    __attribute__((ext_vector_type(2)));
typedef _Float16     h16x8  __attribute__((ext_vector_type(8)));

__device__ __forceinline__ float leaky(float v) { return v >= 0.f ? v : 0.2f * v; }

__device__ __forceinline__ unsigned int pkh2(float x, float y) {
    auto p = __builtin_amdgcn_cvt_pkrtz(x, y);
    return __builtin_bit_cast(unsigned int, p);
}
__device__ __forceinline__ unsigned short f2h(float x) {
    return __builtin_bit_cast(unsigned short, (_Float16)x);
}

// ---------------- Kernel P: fp32 -> fp16 conversion ----------------
__global__ __launch_bounds__(256) void prep_kernel(
    const float* __restrict__ emb,      // [V*E]
    const float* __restrict__ conv_w,   // [2][529][16]
    unsigned int* __restrict__ emb_h,   // [V*E/2] packed half2
    unsigned int* __restrict__ convw_h) // [529*16] packed (w0,w1)
{
    const int gid = blockIdx.x * 256 + threadIdx.x;
    const int stride = gridDim.x * 256;
    for (int i = gid; i < (15245 * 100) / 2; i += stride) {
        const float2 v = ((const float2*)emb)[i];
        emb_h[i] = pkh2(v.x, v.y);
    }
    for (int i = gid; i < LA * NF; i += stride)
        convw_h[i] = pkh2(conv_w[i], conv_w[LA * NF + i]);
}

// ---------------- Kernel A: MFMA conv + relu + maxpool --------------------
// 512 blocks x 256 threads (4 waves), 2 batches/block.
// y[t][f] = sum_k E[t][k] W[k][f], k = 2c+tap (K=1058 pad 1088), M=50 pad 64,
// N=16. Wave (bb = wid>>1, tp = wid&1) computes tiles {2tp, 2tp+1} of its
// batch: per K-chunk one conflict-free ds_read_b128 of the pre-swizzled
// weight fragment (shared by both tiles) + 8 coalesced A-gathers + 2 MFMA.
// A-frag uint j IS emb_h[tok[c]*50 + t] (16 lanes of a quarter share one
// token row, consecutive t -> 4x64B segments). Pool+bias+relu in epilogue
// (C rows are 4 consecutive t per lane -> intra-lane pooling).
__global__ __launch_bounds__(256, 2) void conv_mfma_kernel(
    const int*          __restrict__ tokens,
    const unsigned int* __restrict__ emb_h,   // [V][50] half2 rows
    const unsigned int* __restrict__ convw_h, // [529][16] (w0,w1) half2
    const float*        __restrict__ conv_b,
    float*              __restrict__ p_out)   // [B][25][16]
{
    __shared__ __align__(16) unsigned int wf[NKC * 64 * 4];  // 34.8 KB
    __shared__ int tok2[2 * LA];                             // 4.2 KB

    const int tid  = threadIdx.x;
    const int lane = tid & 63;
    const int wid  = tid >> 6;          // 0..3
    const int bb   = wid >> 1;          // batch half
    const int tp   = wid & 1;           // tile pair
    const int b    = blockIdx.x * 2 + bb;

    // zero-pad entries of the last K-chunk (c = 529..543); c == 528 entries
    // (q==0 && j==0) are written by the stage loop below (no overlap race).
    if (tid < 256) {
        const int j = tid & 3, l = (tid >> 2) & 63;
        if (!(((l >> 4) == 0) && (j == 0)))
            wf[(NKC - 1) * 256 + tid] = 0u;
    }
    // stage weights into MFMA B-fragment layout (coalesced source reads):
    // src i = c*16+f -> dest (s = c>>4, q = (c>>2)&3, j = c&3, l = q*16+f)
    for (int i = tid; i < LA * NF; i += 256) {
        const int c = i >> 4, f = i & 15;
        wf[(((c >> 4) * 64 + ((c >> 2) & 3) * 16 + f) << 2) + (c & 3)] = convw_h[i];
    }
    for (int i = tid; i < 2 * LA; i += 256)
        tok2[i] = tokens[(size_t)blockIdx.x * 2 * LA + i];
    __syncthreads();

    const int r = lane & 15;            // A row offset / B col f
    const int q = lane >> 4;            // k-quarter
    const int m0 = tp * 2, m1 = m0 + 1;
    int tr0 = m0 * 16 + r; tr0 = tr0 > 49 ? 49 : tr0;   // clamp pad rows
    int tr1 = m1 * 16 + r; tr1 = tr1 > 49 ? 49 : tr1;
    const int* __restrict__ tk = tok2 + bb * LA;

    f32x4v ac0 = {0.f, 0.f, 0.f, 0.f}, ac1 = {0.f, 0.f, 0.f, 0.f};

#define LOAD_A(s_, A0, A1) do { \
    const int s2 = (s_); \
    _Pragma("unroll") \
    for (int j = 0; j < 4; ++j) { \
        int c = 16 * s2 + 4 * q + j; \
        if (c >= LA) c = 0; \
        const size_t rowb = (size_t)tk[c] * 50; \
        (A0)[j] = emb_h[rowb + tr0]; \
        (A1)[j] = emb_h[rowb + tr1]; \
    } } while (0)

    u32x4 Aa0, Aa1, Ab0, Ab1, An0, An1;
    LOAD_A(0, Aa0, Aa1);
    LOAD_A(1, Ab0, Ab1);
#pragma unroll
    for (int s = 0; s < NKC; ++s) {
        if (s + 2 < NKC) LOAD_A(s + 2, An0, An1);
        const u32x4 Bv = ((const u32x4*)wf)[s * 64 + lane];
        ac0 = __builtin_amdgcn_mfma_f32_16x16x32_f16(
            __builtin_bit_cast(h16x8, Aa0), __builtin_bit_cast(h16x8, Bv), ac0, 0, 0, 0);
        ac1 = __builtin_amdgcn_mfma_f32_16x16x32_f16(
            __builtin_bit_cast(h16x8, Aa1), __builtin_bit_cast(h16x8, Bv), ac1, 0, 0, 0);
        Aa0 = Ab0; Aa1 = Ab1; Ab0 = An0; Ab1 = An1;
    }
#undef LOAD_A

    // epilogue: bias + relu + maxpool(k=2,s=2); C rows t = m*16 + 4q + reg
    const float bf = conv_b[r];
    {
        const float y0 = fmaxf(ac0[0] + bf, 0.f), y1 = fmaxf(ac0[1] + bf, 0.f);
        const float y2 = fmaxf(ac0[2] + bf, 0.f), y3 = fmaxf(ac0[3] + bf, 0.f);
        const int s0 = m0 * 8 + 2 * q;
        if (s0 < NS)     p_out[(size_t)b * (NS * NF) + s0 * NF + r]       = fmaxf(y0, y1);
        if (s0 + 1 < NS) p_out[(size_t)b * (NS * NF) + (s0 + 1) * NF + r] = fmaxf(y2, y3);
    }
    {
        const float y0 = fmaxf(ac1[0] + bf, 0.f), y1 = fmaxf(ac1[1] + bf, 0.f);
        const float y2 = fmaxf(ac1[2] + bf, 0.f), y3 = fmaxf(ac1[3] + bf, 0.f);
        const int s0 = m1 * 8 + 2 * q;
        if (s0 < NS)     p_out[(size_t)b * (NS * NF) + s0 * NF + r]       = fmaxf(y0, y1);
        if (s0 + 1 < NS) p_out[(size_t)b * (NS * NF) + (s0 + 1) * NF + r] = fmaxf(y2, y3);
    }
}

// ---------------- Kernel B: fp16 MFMA LSTM, 2 tiles/wave ------------------
// (r15 proven: 256 blocks x 896 threads, 4 batches/block, 32-VGPR
// stationary B per wave — the first set the allocator kept resident.)
__global__ __launch_bounds__(896) void lstm_mfma_kernel(
    const float* __restrict__ p_in,    // [B][25][16]
    const float* __restrict__ k_lstm,  // [16][400]
    const float* __restrict__ rk,      // [100][400]
    const float* __restrict__ b_lstm,  // [400]
    const float* __restrict__ w1,      // [100][64]
    const float* __restrict__ b1,      // [64]
    const float* __restrict__ w2,      // [64][3]
    const float* __restrict__ b2,      // [3]
    float*       __restrict__ out)     // [B][3]
{
    __shared__ __align__(16) unsigned short a_lds[2][4][64][8]; // dbuf, 8 KB
    __shared__ __align__(16) float z_lds[NJ][4];                // [j][b], 6.4 KB
    __shared__ float h_f32[4][NU];
    __shared__ float d_lds[4 * 64];

    const int tid  = threadIdx.x;
    const int lane = tid & 63;
    const int wid  = tid >> 6;
    const int b0   = blockIdx.x * 4;

    for (int i = tid; i < 2 * 4 * 64 * 8; i += 896) ((unsigned short*)a_lds)[i] = 0;

    // ---- stationary B-frags (fp16): wave w owns tiles {2w, 2w+1} ----
    h16x8 bfr[2][4];   // [tile][chunk] = 32 VGPR
#pragma unroll
    for (int i = 0; i < 2; ++i) {
        const int ntg = wid * 2 + i;
        if (ntg < 25) {
            const int jg = ntg * 16 + (lane & 15);
#pragma unroll
            for (int c = 0; c < 4; ++c) {
                h16x8 h8;
#pragma unroll
                for (int e = 0; e < 8; ++e) {
                    const int k = c * 32 + (lane >> 4) * 8 + e;
                    float x = 0.f;
                    if (k < NU)        x = rk[k * NJ + jg];
                    else if (k < 116)  x = k_lstm[(k - NU) * NJ + jg];
                    else if (k == 116) x = b_lstm[jg];
                    h8[e] = (_Float16)x;
                }
                bfr[i][c] = h8;
            }
        }
    }
    __syncthreads();   // a_lds zeroing complete

    // initial p (t=0): 64 slots (4 batches x 16); bias slot k=116 both buffers
    if (tid < 64) {
        const int pb = tid >> 4, pf = tid & 15;
        const float pv = p_in[(size_t)(b0 + pb) * (NS * NF) + pf];
        const int k = 100 + pf;
        a_lds[0][k >> 5][(((k >> 3) & 3) << 4) + pb][k & 7] = f2h(pv);
    }
    if (tid < 4) {
        a_lds[0][3][32 + tid][4] = 0x3C00;   // fp16 1.0
        a_lds[1][3][32 + tid][4] = 0x3C00;
    }
    float cst = 0.f;
    const int gb = tid & 3, gu = tid >> 2;   // gate thread (tid < 400)
    __syncthreads();

#pragma unroll 1
    for (int t = 0; t < NS; ++t) {
        const int cur = t & 1, nxt = cur ^ 1;
        // wave 13: prefetch p for t+1 (overlaps compute)
        float pv = 0.f;
        if (tid >= 832 && t + 1 < NS) {
            const int idx = tid - 832, pb = idx >> 4, pf = idx & 15;
            pv = p_in[(size_t)(b0 + pb) * (NS * NF) + (t + 1) * NF + pf];
        }
        if (wid < 13) {   // waves 0..12 compute
            h16x8 ah[4];
#pragma unroll
            for (int c = 0; c < 4; ++c)
                ah[c] = __builtin_bit_cast(h16x8, ((const s16x8*)a_lds[cur][c])[lane]);
#pragma unroll
            for (int i = 0; i < 2; ++i) {
                const int ntg = wid * 2 + i;
                if (ntg < 25) {
                    f32x4v z0 = {0.f, 0.f, 0.f, 0.f}, z1 = {0.f, 0.f, 0.f, 0.f};
                    z0 = __builtin_amdgcn_mfma_f32_16x16x32_f16(ah[0], bfr[i][0], z0, 0, 0, 0);
                    z1 = __builtin_amdgcn_mfma_f32_16x16x32_f16(ah[1], bfr[i][1], z1, 0, 0, 0);
                    z0 = __builtin_amdgcn_mfma_f32_16x16x32_f16(ah[2], bfr[i][2], z0, 0, 0, 0);
                    z1 = __builtin_amdgcn_mfma_f32_16x16x32_f16(ah[3], bfr[i][3], z1, 0, 0, 0);
                    const f32x4v acc = z0 + z1;
                    if (lane < 16) {   // rows 0..3 = real batches
                        *((f32x4v*)z_lds[ntg * 16 + lane]) = acc;
                    }
                }
            }
        }
        __syncthreads();
        // gates: thread -> (b = tid&3, u = tid>>2)
        if (tid < 4 * NU) {
            const float zi = z_lds[gu][gb];
            const float zf = z_lds[gu + 100][gb];
            const float zg = z_lds[gu + 200][gb];
            const float zo = z_lds[gu + 300][gb];
            const float ig  = 1.f / (1.f + __expf(-zi));
            const float fg_ = 1.f / (1.f + __expf(-zf));
            const float og  = 1.f / (1.f + __expf(-zo));
            cst = fg_ * cst + ig * leaky(zg);
            const float h = og * leaky(cst);
            h_f32[gb][gu] = h;
            const int c = gu >> 5, ls = (((gu >> 3) & 3) << 4) + gb, e = gu & 7;
            a_lds[nxt][c][ls][e] = f2h(h);
        }
        if (tid >= 832 && t + 1 < NS) {   // write p slots for t+1
            const int idx = tid - 832, pb = idx >> 4, pf = idx & 15;
            const int k = 100 + pf;
            a_lds[nxt][k >> 5][(((k >> 3) & 3) << 4) + pb][k & 7] = f2h(pv);
        }
        __syncthreads();
    }

    // dense head: d = tanh(h @ w1 + b1)
    if (tid < 256) {
        const int hb = tid >> 6, m = tid & 63;
        float a = b1[m];
#pragma unroll 4
        for (int u = 0; u < NU; ++u) a += h_f32[hb][u] * w1[u * 64 + m];
        d_lds[hb * 64 + m] = tanhf(a);
    }
    __syncthreads();

    // logits + softmax (3 classes)
    if (tid < 4) {
        float l0 = b2[0], l1 = b2[1], l2 = b2[2];
        for (int m = 0; m < 64; ++m) {
            const float d = d_lds[tid * 64 + m];
            l0 += d * w2[m * 3 + 0];
            l1 += d * w2[m * 3 + 1];
            l2 += d * w2[m * 3 + 2];
        }
        const float mx = fmaxf(l0, fmaxf(l1, l2));
        const float e0 = __expf(l0 - mx), e1 = __expf(l1 - mx), e2 = __expf(l2 - mx);
        const float inv = 1.f / (e0 + e1 + e2);
        out[(b0 + tid) * 3 + 0] = e0 * inv;
        out[(b0 + tid) * 3 + 1] = e1 * inv;
        out[(b0 + tid) * 3 + 2] = e2 * inv;
    }
}

extern "C" void kernel_launch(void* const* d_in, const int* in_sizes, int n_in,
                              void* d_out, int out_size, void* d_ws, size_t ws_size,
                              hipStream_t stream) {
    const int*   tokens = (const int*)  d_in[0];
    const float* emb    = (const float*)d_in[1];
    const float* conv_w = (const float*)d_in[2];
    const float* conv_b = (const float*)d_in[3];
    const float* k_lstm = (const float*)d_in[4];
    const float* rk     = (const float*)d_in[5];
    const float* b_lstm = (const float*)d_in[6];
    const float* w1     = (const float*)d_in[7];
    const float* b1     = (const float*)d_in[8];
    const float* w2     = (const float*)d_in[9];
    const float* b2     = (const float*)d_in[10];
    float* out = (float*)d_out;

    // ws layout (bytes): p[1024][25][16] f32 : [0, 1638400)
    //                    emb_h (half2)       : [1638400, 4687400) -> align 4687408
    //                    convw_h (half2)     : [4687408, 4721264)
    char* ws = (char*)d_ws;
    float*        p_ws    = (float*)ws;
    unsigned int* emb_h   = (unsigned int*)(ws + 1638400);
    unsigned int* convw_h = (unsigned int*)(ws + 4687408);

    prep_kernel<<<1024, 256, 0, stream>>>(emb, conv_w, emb_h, convw_h);
    conv_mfma_kernel<<<B_ / 2, 256, 0, stream>>>(tokens, emb_h, convw_h, conv_b, p_ws);
    lstm_mfma_kernel<<<B_ / 4, 896, 0, stream>>>(p_ws, k_lstm, rk, b_lstm,
                                                 w1, b1, w2, b2, out);
}

// Round 20
// 52.430 us; speedup vs baseline: 2.0265x; 1.1041x over previous
//
#include <hip/hip_runtime.h>
#include <hip/hip_bf16.h>

#define B_  1024
#define LA  529   // token positions -> conv channels
#define EE  100   // embedding dim -> conv steps
#define NF  16    // conv filters
#define NT  50    // conv output steps
#define NS  25    // pooled steps
#define NU  100   // LSTM units
#define NJ  400   // 4*NU
#define NKC 34    // conv K-chunks of 32 (K = 2*529 = 1058, padded 1088)

typedef float        f32x4v __attribute__((ext_vector_type(4)));
typedef short        s16x8  __attribute__((ext_vector_type(8)));
typedef unsigned int u32x4  __attribute__((ext_vector_type(4)));
typedef _Float16     h2v    __attribute__((ext_vector_type(2)));
typedef _Float16     h16x8  __attribute__((ext_vector_type(8)));

__device__ __forceinline__ float leaky(float v) { return v >= 0.f ? v : 0.2f * v; }

__device__ __forceinline__ unsigned int pkh2(float x, float y) {
    auto p = __builtin_amdgcn_cvt_pkrtz(x, y);
    return __builtin_bit_cast(unsigned int, p);
}
__device__ __forceinline__ unsigned short f2h(float x) {
    return __builtin_bit_cast(unsigned short, (_Float16)x);
}

// ---------------- Kernel P: fp32 -> fp16 conversion + W_aug fragment image -
__global__ __launch_bounds__(256) void prep_kernel(
    const float* __restrict__ emb,      // [V*E]
    const float* __restrict__ conv_w,   // [2][529][16]
    const float* __restrict__ k_lstm,   // [16][400]
    const float* __restrict__ rk,       // [100][400]
    const float* __restrict__ b_lstm,   // [400]
    unsigned int*   __restrict__ emb_h,   // [V*E/2] packed half2
    unsigned int*   __restrict__ convw_h, // [529*16] packed (w0,w1)
    unsigned short* __restrict__ wfl)     // [25*2048] W_aug fp16 fragment image
{
    const int gid = blockIdx.x * 256 + threadIdx.x;
    const int stride = gridDim.x * 256;
    for (int i = gid; i < (15245 * 100) / 2; i += stride) {
        const float2 v = ((const float2*)emb)[i];
        emb_h[i] = pkh2(v.x, v.y);
    }
    for (int i = gid; i < LA * NF; i += stride)
        convw_h[i] = pkh2(conv_w[i], conv_w[LA * NF + i]);
    // W_aug in MFMA B-fragment layout: n = ((tile*4 + c)*64 + l)*8 + e;
    // col jg = tile*16 + (l&15), k = c*32 + (l>>4)*8 + e.
    for (int n = gid; n < 25 * 2048; n += stride) {
        const int tile = n >> 11, c = (n >> 9) & 3, l = (n >> 3) & 63, e = n & 7;
        const int jg = tile * 16 + (l & 15);
        const int k  = c * 32 + ((l >> 4) << 3) + e;
        float x = 0.f;
        if (k < NU)        x = rk[k * NJ + jg];
        else if (k < 116)  x = k_lstm[(k - NU) * NJ + jg];
        else if (k == 116) x = b_lstm[jg];
        wfl[n] = f2h(x);
    }
}

// ---------------- Kernel A: MFMA conv + relu + maxpool --------------------
// (r19 proven, ~14us: 512 blocks x 256 threads, 2 batches/block; per K-chunk
// one conflict-free ds_read_b128 B-frag + coalesced A-gathers + 2 MFMA.)
__global__ __launch_bounds__(256, 2) void conv_mfma_kernel(
    const int*          __restrict__ tokens,
    const unsigned int* __restrict__ emb_h,   // [V][50] half2 rows
    const unsigned int* __restrict__ convw_h, // [529][16] (w0,w1) half2
    const float*        __restrict__ conv_b,
    float*              __restrict__ p_out)   // [B][25][16]
{
    __shared__ __align__(16) unsigned int wf[NKC * 64 * 4];  // 34.8 KB
    __shared__ int tok2[2 * LA];                             // 4.2 KB

    const int tid  = threadIdx.x;
    const int lane = tid & 63;
    const int wid  = tid >> 6;          // 0..3
    const int bb   = wid >> 1;          // batch half
    const int tp   = wid & 1;           // tile pair
    const int b    = blockIdx.x * 2 + bb;

    if (tid < 256) {
        const int j = tid & 3, l = (tid >> 2) & 63;
        if (!(((l >> 4) == 0) && (j == 0)))
            wf[(NKC - 1) * 256 + tid] = 0u;
    }
    for (int i = tid; i < LA * NF; i += 256) {
        const int c = i >> 4, f = i & 15;
        wf[(((c >> 4) * 64 + ((c >> 2) & 3) * 16 + f) << 2) + (c & 3)] = convw_h[i];
    }
    for (int i = tid; i < 2 * LA; i += 256)
        tok2[i] = tokens[(size_t)blockIdx.x * 2 * LA + i];
    __syncthreads();

    const int r = lane & 15;            // A row offset / B col f
    const int q = lane >> 4;            // k-quarter
    const int m0 = tp * 2, m1 = m0 + 1;
    int tr0 = m0 * 16 + r; tr0 = tr0 > 49 ? 49 : tr0;
    int tr1 = m1 * 16 + r; tr1 = tr1 > 49 ? 49 : tr1;
    const int* __restrict__ tk = tok2 + bb * LA;

    f32x4v ac0 = {0.f, 0.f, 0.f, 0.f}, ac1 = {0.f, 0.f, 0.f, 0.f};

#define LOAD_A(s_, A0, A1) do { \
    const int s2 = (s_); \
    _Pragma("unroll") \
    for (int j = 0; j < 4; ++j) { \
        int c = 16 * s2 + 4 * q + j; \
        if (c >= LA) c = 0; \
        const size_t rowb = (size_t)tk[c] * 50; \
        (A0)[j] = emb_h[rowb + tr0]; \
        (A1)[j] = emb_h[rowb + tr1]; \
    } } while (0)

    u32x4 Aa0, Aa1, Ab0, Ab1, An0, An1;
    LOAD_A(0, Aa0, Aa1);
    LOAD_A(1, Ab0, Ab1);
#pragma unroll
    for (int s = 0; s < NKC; ++s) {
        if (s + 2 < NKC) LOAD_A(s + 2, An0, An1);
        const u32x4 Bv = ((const u32x4*)wf)[s * 64 + lane];
        ac0 = __builtin_amdgcn_mfma_f32_16x16x32_f16(
            __builtin_bit_cast(h16x8, Aa0), __builtin_bit_cast(h16x8, Bv), ac0, 0, 0, 0);
        ac1 = __builtin_amdgcn_mfma_f32_16x16x32_f16(
            __builtin_bit_cast(h16x8, Aa1), __builtin_bit_cast(h16x8, Bv), ac1, 0, 0, 0);
        Aa0 = Ab0; Aa1 = Ab1; Ab0 = An0; Ab1 = An1;
    }
#undef LOAD_A

    const float bf = conv_b[r];
    {
        const float y0 = fmaxf(ac0[0] + bf, 0.f), y1 = fmaxf(ac0[1] + bf, 0.f);
        const float y2 = fmaxf(ac0[2] + bf, 0.f), y3 = fmaxf(ac0[3] + bf, 0.f);
        const int s0 = m0 * 8 + 2 * q;
        if (s0 < NS)     p_out[(size_t)b * (NS * NF) + s0 * NF + r]       = fmaxf(y0, y1);
        if (s0 + 1 < NS) p_out[(size_t)b * (NS * NF) + (s0 + 1) * NF + r] = fmaxf(y2, y3);
    }
    {
        const float y0 = fmaxf(ac1[0] + bf, 0.f), y1 = fmaxf(ac1[1] + bf, 0.f);
        const float y2 = fmaxf(ac1[2] + bf, 0.f), y3 = fmaxf(ac1[3] + bf, 0.f);
        const int s0 = m1 * 8 + 2 * q;
        if (s0 < NS)     p_out[(size_t)b * (NS * NF) + s0 * NF + r]       = fmaxf(y0, y1);
        if (s0 + 1 < NS) p_out[(size_t)b * (NS * NF) + (s0 + 1) * NF + r] = fmaxf(y2, y3);
    }
}

// ---------------- Kernel B: fp16 MFMA LSTM, prepped B-frag image ----------
// 256 blocks x 896 threads, 4 batches/block. B-frags now load from the
// pre-swizzled fp16 global image (8 coalesced dwordx4/lane, no cvt chain):
// if the allocator sinks them into the loop (it always has), the remat is
// 8 same-address L1-resident vector loads instead of 64 scattered fp32
// loads + converts — the ~3830 cy/step that held LSTM at 40us since r4.
__global__ __launch_bounds__(896) void lstm_mfma_kernel(
    const float* __restrict__ p_in,    // [B][25][16]
    const unsigned short* __restrict__ wfl,  // [25*2048] W_aug fragment image
    const float* __restrict__ w1,      // [100][64]
    const float* __restrict__ b1,      // [64]
    const float* __restrict__ w2,      // [64][3]
    const float* __restrict__ b2,      // [3]
    float*       __restrict__ out)     // [B][3]
{
    __shared__ __align__(16) unsigned short a_lds[2][4][64][8]; // dbuf, 8 KB
    __shared__ __align__(16) float z_lds[NJ][4];                // [j][b], 6.4 KB
    __shared__ float h_f32[4][NU];
    __shared__ float d_lds[4 * 64];

    const int tid  = threadIdx.x;
    const int lane = tid & 63;
    const int wid  = tid >> 6;
    const int b0   = blockIdx.x * 4;

    for (int i = tid; i < 2 * 4 * 64 * 8; i += 896) ((unsigned short*)a_lds)[i] = 0;

    // ---- stationary B-frags: 8 coalesced dwordx4 from the prepped image ----
    const int t0 = (wid * 2     < 25) ? wid * 2     : 0;
    const int t1 = (wid * 2 + 1 < 25) ? wid * 2 + 1 : 0;
    h16x8 bfr[2][4];   // 32 VGPR
#pragma unroll
    for (int c = 0; c < 4; ++c) {
        bfr[0][c] = __builtin_bit_cast(h16x8,
            ((const s16x8*)wfl)[(t0 * 4 + c) * 64 + lane]);
        bfr[1][c] = __builtin_bit_cast(h16x8,
            ((const s16x8*)wfl)[(t1 * 4 + c) * 64 + lane]);
    }
    __syncthreads();   // a_lds zeroing complete

    // initial p (t=0): 64 slots (4 batches x 16); bias slot k=116 both buffers
    if (tid < 64) {
        const int pb = tid >> 4, pf = tid & 15;
        const float pv = p_in[(size_t)(b0 + pb) * (NS * NF) + pf];
        const int k = 100 + pf;
        a_lds[0][k >> 5][(((k >> 3) & 3) << 4) + pb][k & 7] = f2h(pv);
    }
    if (tid < 4) {
        a_lds[0][3][32 + tid][4] = 0x3C00;   // fp16 1.0
        a_lds[1][3][32 + tid][4] = 0x3C00;
    }
    float cst = 0.f;
    const int gb = tid & 3, gu = tid >> 2;   // gate thread (tid < 400)
    __syncthreads();

#pragma unroll 1
    for (int t = 0; t < NS; ++t) {
        const int cur = t & 1, nxt = cur ^ 1;
        // wave 13: prefetch p for t+1 (overlaps compute)
        float pv = 0.f;
        if (tid >= 832 && t + 1 < NS) {
            const int idx = tid - 832, pb = idx >> 4, pf = idx & 15;
            pv = p_in[(size_t)(b0 + pb) * (NS * NF) + (t + 1) * NF + pf];
        }
        if (wid < 13) {   // waves 0..12 compute
            h16x8 ah[4];
#pragma unroll
            for (int c = 0; c < 4; ++c)
                ah[c] = __builtin_bit_cast(h16x8, ((const s16x8*)a_lds[cur][c])[lane]);
#pragma unroll
            for (int i = 0; i < 2; ++i) {
                const int ntg = wid * 2 + i;
                if (ntg < 25) {
                    f32x4v z0 = {0.f, 0.f, 0.f, 0.f}, z1 = {0.f, 0.f, 0.f, 0.f};
                    z0 = __builtin_amdgcn_mfma_f32_16x16x32_f16(ah[0], bfr[i][0], z0, 0, 0, 0);
                    z1 = __builtin_amdgcn_mfma_f32_16x16x32_f16(ah[1], bfr[i][1], z1, 0, 0, 0);
                    z0 = __builtin_amdgcn_mfma_f32_16x16x32_f16(ah[2], bfr[i][2], z0, 0, 0, 0);
                    z1 = __builtin_amdgcn_mfma_f32_16x16x32_f16(ah[3], bfr[i][3], z1, 0, 0, 0);
                    const f32x4v acc = z0 + z1;
                    if (lane < 16) {   // rows 0..3 = real batches
                        *((f32x4v*)z_lds[ntg * 16 + lane]) = acc;
                    }
                }
            }
        }
        __syncthreads();
        // gates: thread -> (b = tid&3, u = tid>>2)
        if (tid < 4 * NU) {
            const float zi = z_lds[gu][gb];
            const float zf = z_lds[gu + 100][gb];
            const float zg = z_lds[gu + 200][gb];
            const float zo = z_lds[gu + 300][gb];
            const float ig  = 1.f / (1.f + __expf(-zi));
            const float fg_ = 1.f / (1.f + __expf(-zf));
            const float og  = 1.f / (1.f + __expf(-zo));
            cst = fg_ * cst + ig * leaky(zg);
            const float h = og * leaky(cst);
            h_f32[gb][gu] = h;
            const int c = gu >> 5, ls = (((gu >> 3) & 3) << 4) + gb, e = gu & 7;
            a_lds[nxt][c][ls][e] = f2h(h);
        }
        if (tid >= 832 && t + 1 < NS) {   // write p slots for t+1
            const int idx = tid - 832, pb = idx >> 4, pf = idx & 15;
            const int k = 100 + pf;
            a_lds[nxt][k >> 5][(((k >> 3) & 3) << 4) + pb][k & 7] = f2h(pv);
        }
        __syncthreads();
    }

    // dense head: d = tanh(h @ w1 + b1)
    if (tid < 256) {
        const int hb = tid >> 6, m = tid & 63;
        float a = b1[m];
#pragma unroll 4
        for (int u = 0; u < NU; ++u) a += h_f32[hb][u] * w1[u * 64 + m];
        d_lds[hb * 64 + m] = tanhf(a);
    }
    __syncthreads();

    // logits + softmax (3 classes)
    if (tid < 4) {
        float l0 = b2[0], l1 = b2[1], l2 = b2[2];
        for (int m = 0; m < 64; ++m) {
            const float d = d_lds[tid * 64 + m];
            l0 += d * w2[m * 3 + 0];
            l1 += d * w2[m * 3 + 1];
            l2 += d * w2[m * 3 + 2];
        }
        const float mx = fmaxf(l0, fmaxf(l1, l2));
        const float e0 = __expf(l0 - mx), e1 = __expf(l1 - mx), e2 = __expf(l2 - mx);
        const float inv = 1.f / (e0 + e1 + e2);
        out[(b0 + tid) * 3 + 0] = e0 * inv;
        out[(b0 + tid) * 3 + 1] = e1 * inv;
        out[(b0 + tid) * 3 + 2] = e2 * inv;
    }
}

extern "C" void kernel_launch(void* const* d_in, const int* in_sizes, int n_in,
                              void* d_out, int out_size, void* d_ws, size_t ws_size,
                              hipStream_t stream) {
    const int*   tokens = (const int*)  d_in[0];
    const float* emb    = (const float*)d_in[1];
    const float* conv_w = (const float*)d_in[2];
    const float* conv_b = (const float*)d_in[3];
    const float* k_lstm = (const float*)d_in[4];
    const float* rk     = (const float*)d_in[5];
    const float* b_lstm = (const float*)d_in[6];
    const float* w1     = (const float*)d_in[7];
    const float* b1     = (const float*)d_in[8];
    const float* w2     = (const float*)d_in[9];
    const float* b2     = (const float*)d_in[10];
    float* out = (float*)d_out;

    // ws layout (bytes): p[1024][25][16] f32 : [0, 1638400)
    //                    emb_h (half2)       : [1638400, 4687400) -> align 4687408
    //                    convw_h (half2)     : [4687408, 4721264) -> align 4721280
    //                    wfl (fp16 frag img) : [4721280, 4823680)
    char* ws = (char*)d_ws;
    float*          p_ws    = (float*)ws;
    unsigned int*   emb_h   = (unsigned int*)(ws + 1638400);
    unsigned int*   convw_h = (unsigned int*)(ws + 4687408);
    unsigned short* wfl     = (unsigned short*)(ws + 4721280);

    prep_kernel<<<1024, 256, 0, stream>>>(emb, conv_w, k_lstm, rk, b_lstm,
                                          emb_h, convw_h, wfl);
    conv_mfma_kernel<<<B_ / 2, 256, 0, stream>>>(tokens, emb_h, convw_h, conv_b, p_ws);
    lstm_mfma_kernel<<<B_ / 4, 896, 0, stream>>>(p_ws, wfl, w1, b1, w2, b2, out);
}